// Round 3
// baseline (13354.883 us; speedup 1.0000x reference)
//
#include <hip/hip_runtime.h>
#include <math.h>

#ifndef M_PI
#define M_PI 3.14159265358979323846
#endif

#define BD 256
#define NB 16
#define DIM 1024
#define SMAX 288
#define NSTEPS 32
#define NPROPS 512
#define NTOK (16 * 256 * 1024)
#define NCH 9

__device__ __forceinline__ double wred_sum(double v) {
#pragma unroll
    for (int o = 32; o > 0; o >>= 1) v += __shfl_down(v, o, 64);
    return v;
}
__device__ double block_sum(double v, double* sc) {
    v = wred_sum(v);
    int tid = threadIdx.x;
    if ((tid & 63) == 0) sc[tid >> 6] = v;
    __syncthreads();
    double r = sc[0] + sc[1] + sc[2] + sc[3];
    __syncthreads();
    return r;
}
// per-wave LN stats for one row of length DIM
__device__ __forceinline__ void wave_ln_stats(const double* __restrict__ xrow,
                                              double* mu_s, double* rs_s, int r, int lane) {
    double s = 0;
    for (int i = lane; i < DIM; i += 64) s += xrow[i];
    s = wred_sum(s);
    double m = __shfl(s, 0, 64) * (1.0 / 1024.0);
    double ss = 0;
    for (int i = lane; i < DIM; i += 64) { double d = xrow[i] - m; ss += d * d; }
    ss = wred_sum(ss);
    if (lane == 0) { mu_s[r] = m; rs_s[r] = 1.0 / sqrt(ss * (1.0 / 1024.0) + 1e-5); }
}

// ---- canonicalize tokens: handles harness passing int32 OR raw int64 ----
__global__ __launch_bounds__(256) void k_tok_convert(const int* __restrict__ tok32,
                                                     signed char* __restrict__ tokc) {
    __shared__ int flag;
    int tid = threadIdx.x;
    if (tid == 0) {
        int nz = 0;
        for (int i = 1; i < 512; i += 2) nz |= tok32[i];
        flag = nz;
    }
    __syncthreads();
    bool is64 = (flag == 0);
#pragma unroll
    for (int it = 0; it < 4; ++it) {
        size_t idx = (size_t)blockIdx.x * 1024 + it * BD + tid;
        int v = is64 ? tok32[2 * idx] : tok32[idx];
        tokc[idx] = (signed char)v;
    }
}

// ---- prefix LN stats ----
__global__ __launch_bounds__(256) void k_prefix_stats(const signed char* __restrict__ tokc,
                                                      double* __restrict__ mu, double* __restrict__ rs) {
    __shared__ double sc[4];
    int T = blockIdx.x, tid = threadIdx.x;
    const signed char* row = tokc + (size_t)T * DIM;
    double s = 0;
    for (int i = tid; i < DIM; i += BD) s += (double)row[i];
    s = block_sum(s, sc);
    double m = s * (1.0 / 1024.0);
    double ss = 0;
    for (int i = tid; i < DIM; i += BD) { double d = (double)row[i] - m; ss += d * d; }
    ss = block_sum(ss, sc);
    if (tid == 0) { mu[T] = m; rs[T] = 1.0 / sqrt(ss * (1.0 / 1024.0) + 1e-5); }
}

__global__ __launch_bounds__(256) void k_init_xl(const signed char* __restrict__ tokc, double* __restrict__ xl) {
    int b = blockIdx.x, tid = threadIdx.x;
    for (int i = tid; i < DIM; i += BD)
        xl[b * DIM + i] = (double)tokc[((size_t)b * 256 + 255) * DIM + i];
}

// ---- prefix K,V GEMM (unchanged from passing R2 version) ----
__global__ __launch_bounds__(256) void k_prefix(const signed char* __restrict__ tokc,
        const double* __restrict__ mu, const double* __restrict__ rs,
        const float* __restrict__ Wqkv, const float* __restrict__ bqkv,
        const float* __restrict__ g1, const float* __restrict__ b1,
        double* __restrict__ Kc, double* __restrict__ Vc) {
    __shared__ double Hs[64 * 17];
    __shared__ float  Ws[64 * 64];
    int tid = threadIdx.x;
    int tx = tid & 63, ty = tid >> 6;
    int j0 = blockIdx.x * 64;
    int T0 = blockIdx.y * 16;
    double acc[4] = {0, 0, 0, 0};
    for (int kc = 0; kc < DIM; kc += 64) {
#pragma unroll
        for (int it = 0; it < 4; ++it) {
            int idx = tid + it * BD;
            int t = idx & 15, k = idx >> 4;
            int T = T0 + t;
            double x = (double)tokc[(size_t)T * DIM + kc + k];
            Hs[k * 17 + t] = (x - mu[T]) * rs[T] * (double)g1[kc + k] + (double)b1[kc + k];
        }
#pragma unroll
        for (int it = 0; it < 16; ++it) {
            int idx = tid + it * BD;
            int k = idx >> 6, j = idx & 63;
            Ws[k * 64 + j] = Wqkv[(size_t)(kc + k) * 3072 + 1024 + j0 + j];
        }
        __syncthreads();
#pragma unroll 8
        for (int k = 0; k < 64; ++k) {
            double w = (double)Ws[k * 64 + tx];
            acc[0] += Hs[k * 17 + ty * 4 + 0] * w;
            acc[1] += Hs[k * 17 + ty * 4 + 1] * w;
            acc[2] += Hs[k * 17 + ty * 4 + 2] * w;
            acc[3] += Hs[k * 17 + ty * 4 + 3] * w;
        }
        __syncthreads();
    }
    int colg = j0 + tx;
    double bias = (double)bqkv[1024 + colg];
    bool isK = (colg < 1024);
#pragma unroll
    for (int a = 0; a < 4; ++a) {
        int T = T0 + ty * 4 + a;
        int b = T >> 8, pos = T & 255;
        double v = acc[a] + bias;
        if (isK) Kc[((size_t)b * SMAX + pos) * DIM + colg] = v;
        else     Vc[((size_t)b * SMAX + pos) * DIM + colg - 1024] = v;
    }
}

// ---- STEP K1: fused ln1 + qkv GEMM (full K) + bias + scatter q/K/V ----
__global__ __launch_bounds__(256) void k_qkv(const double* __restrict__ xl,
        const float* __restrict__ g1, const float* __restrict__ b1,
        const float* __restrict__ Wqkv, const float* __restrict__ bqkv,
        double* __restrict__ q, double* __restrict__ Kc, double* __restrict__ Vc, int pos) {
    __shared__ double Hs[16 * 65];
    __shared__ float  Ws[64 * 32];
    __shared__ double mu_s[16], rs_s[16];
    int tid = threadIdx.x, lane = tid & 63, wv = tid >> 6;
    for (int rr = 0; rr < 4; ++rr) { int r = wv * 4 + rr; wave_ln_stats(xl + r * DIM, mu_s, rs_s, r, lane); }
    __syncthreads();
    int tx = tid & 31, ty = tid >> 5;
    int j0 = blockIdx.x * 32;
    double acc0 = 0, acc1 = 0;
    for (int kc = 0; kc < DIM; kc += 64) {
#pragma unroll
        for (int it = 0; it < 4; ++it) {
            int idx = tid + it * BD; int r = idx >> 6, k = idx & 63;
            double x = xl[r * DIM + kc + k];
            Hs[r * 65 + k] = (x - mu_s[r]) * rs_s[r] * (double)g1[kc + k] + (double)b1[kc + k];
        }
#pragma unroll
        for (int it = 0; it < 8; ++it) {
            int idx = tid + it * BD; int k = idx >> 5, j = idx & 31;
            Ws[k * 32 + j] = Wqkv[(size_t)(kc + k) * 3072 + j0 + j];
        }
        __syncthreads();
#pragma unroll 16
        for (int k = 0; k < 64; ++k) {
            double w = (double)Ws[k * 32 + tx];
            acc0 += Hs[(ty * 2 + 0) * 65 + k] * w;
            acc1 += Hs[(ty * 2 + 1) * 65 + k] * w;
        }
        __syncthreads();
    }
    int col = j0 + tx;
    double bias = (double)bqkv[col];
    double v0 = acc0 + bias, v1 = acc1 + bias;
    int r0 = ty * 2, r1 = r0 + 1;
    if (col < 1024) {
        q[r0 * DIM + col] = v0; q[r1 * DIM + col] = v1;
    } else if (col < 2048) {
        int cc = col - 1024;
        Kc[((size_t)r0 * SMAX + pos) * DIM + cc] = v0;
        Kc[((size_t)r1 * SMAX + pos) * DIM + cc] = v1;
    } else {
        int cc = col - 2048;
        Vc[((size_t)r0 * SMAX + pos) * DIM + cc] = v0;
        Vc[((size_t)r1 * SMAX + pos) * DIM + cc] = v1;
    }
}

// ---- STEP K2: chunked scores + local softmax + PV partial ----
__global__ __launch_bounds__(256) void k_attn_pv(const double* __restrict__ q,
        const double* __restrict__ Kc, const double* __restrict__ Vc,
        double* __restrict__ oC, double* __restrict__ mlC, int S) {
    __shared__ double qs[DIM];
    __shared__ double ps[32];
    int b = blockIdx.x, c = blockIdx.y, tid = threadIdx.x;
    int lane = tid & 63, w = tid >> 6;
    int pos0 = c * 32;
    for (int i = tid; i < DIM; i += BD) qs[i] = q[b * DIM + i];
    __syncthreads();
    for (int r = 0; r < 8; ++r) {
        int p = w * 8 + r, pos = pos0 + p;
        double d = -1e300;
        if (pos < S) {
            const double* kp = Kc + ((size_t)b * SMAX + pos) * DIM;
            double a = 0;
#pragma unroll
            for (int i = 0; i < 16; ++i) a += qs[lane + 64 * i] * kp[lane + 64 * i];
            a = wred_sum(a);
            d = a * 0.03125;
        }
        if (lane == 0) ps[p] = d;
    }
    __syncthreads();
    int nv = S - pos0;
    if (nv > 32) nv = 32;
    double m = -1e300, l = 0;
    for (int j = 0; j < 32; ++j) { double v = ps[j]; if (j < nv && v > m) m = v; }
    for (int j = 0; j < 32; ++j) { if (j < nv) l += exp(ps[j] - m); }
    __syncthreads();
    if (tid < 32) ps[tid] = (tid < nv) ? exp(ps[tid] - m) : 0.0;
    __syncthreads();
    double a0 = 0, a1 = 0, a2 = 0, a3 = 0;
    for (int j = 0; j < 32; ++j) {
        double e = ps[j];
        const double* vp = Vc + ((size_t)b * SMAX + pos0 + j) * DIM;
        a0 += e * vp[tid];       a1 += e * vp[tid + 256];
        a2 += e * vp[tid + 512]; a3 += e * vp[tid + 768];
    }
    size_t ob = ((size_t)b * NCH + c) * DIM;
    oC[ob + tid] = a0; oC[ob + tid + 256] = a1;
    oC[ob + tid + 512] = a2; oC[ob + tid + 768] = a3;
    if (tid == 0) { mlC[(b * NCH + c) * 2] = m; mlC[(b * NCH + c) * 2 + 1] = l; }
}

// ---- STEP K3a: cross-chunk softmax combine -> ao ----
__global__ __launch_bounds__(256) void k_ao_combine(const double* __restrict__ oC,
        const double* __restrict__ mlC, double* __restrict__ ao) {
    int b = blockIdx.x, tid = threadIdx.x;
    double mv[NCH], lv[NCH], wc[NCH];
    double M = -1e300;
    for (int c = 0; c < NCH; ++c) {
        mv[c] = mlC[(b * NCH + c) * 2];
        lv[c] = mlC[(b * NCH + c) * 2 + 1];
        if (mv[c] > M) M = mv[c];
    }
    double den = 0;
    for (int c = 0; c < NCH; ++c) { wc[c] = exp(mv[c] - M); den += wc[c] * lv[c]; }
    for (int d = tid; d < DIM; d += BD) {
        double s = 0;
        for (int c = 0; c < NCH; ++c) s += wc[c] * oC[((size_t)b * NCH + c) * DIM + d];
        ao[b * DIM + d] = s / den;
    }
}

// ---- STEP K3b: aproj GEMM (full K) + bias + residual -> x2 ----
__global__ __launch_bounds__(256) void k_aproj(const double* __restrict__ ao,
        const float* __restrict__ Wap, const float* __restrict__ bap,
        const double* __restrict__ xl, double* __restrict__ x2) {
    __shared__ double Hs[16 * 65];
    __shared__ float  Ws[64 * 32];
    int tid = threadIdx.x;
    int tx = tid & 31, ty = tid >> 5;
    int j0 = blockIdx.x * 32;
    double acc0 = 0, acc1 = 0;
    for (int kc = 0; kc < DIM; kc += 64) {
#pragma unroll
        for (int it = 0; it < 4; ++it) {
            int idx = tid + it * BD; int r = idx >> 6, k = idx & 63;
            Hs[r * 65 + k] = ao[r * DIM + kc + k];
        }
#pragma unroll
        for (int it = 0; it < 8; ++it) {
            int idx = tid + it * BD; int k = idx >> 5, j = idx & 31;
            Ws[k * 32 + j] = Wap[(size_t)(kc + k) * DIM + j0 + j];
        }
        __syncthreads();
#pragma unroll 16
        for (int k = 0; k < 64; ++k) {
            double w = (double)Ws[k * 32 + tx];
            acc0 += Hs[(ty * 2 + 0) * 65 + k] * w;
            acc1 += Hs[(ty * 2 + 1) * 65 + k] * w;
        }
        __syncthreads();
    }
    int col = j0 + tx;
    double bias = (double)bap[col];
    int r0 = ty * 2, r1 = r0 + 1;
    x2[r0 * DIM + col] = xl[r0 * DIM + col] + acc0 + bias;
    x2[r1 * DIM + col] = xl[r1 * DIM + col] + acc1 + bias;
}

// ---- STEP K4: fused ln2 + fc GEMM + bias + gelu -> m ----
__global__ __launch_bounds__(256) void k_fc(const double* __restrict__ x2,
        const float* __restrict__ g2, const float* __restrict__ b2,
        const float* __restrict__ Wfc, const float* __restrict__ bfc,
        double* __restrict__ mb) {
    __shared__ double Hs[16 * 65];
    __shared__ float  Ws[64 * 32];
    __shared__ double mu_s[16], rs_s[16];
    int tid = threadIdx.x, lane = tid & 63, wv = tid >> 6;
    for (int rr = 0; rr < 4; ++rr) { int r = wv * 4 + rr; wave_ln_stats(x2 + r * DIM, mu_s, rs_s, r, lane); }
    __syncthreads();
    int tx = tid & 31, ty = tid >> 5;
    int j0 = blockIdx.x * 32;
    double acc0 = 0, acc1 = 0;
    for (int kc = 0; kc < DIM; kc += 64) {
#pragma unroll
        for (int it = 0; it < 4; ++it) {
            int idx = tid + it * BD; int r = idx >> 6, k = idx & 63;
            double x = x2[r * DIM + kc + k];
            Hs[r * 65 + k] = (x - mu_s[r]) * rs_s[r] * (double)g2[kc + k] + (double)b2[kc + k];
        }
#pragma unroll
        for (int it = 0; it < 8; ++it) {
            int idx = tid + it * BD; int k = idx >> 5, j = idx & 31;
            Ws[k * 32 + j] = Wfc[(size_t)(kc + k) * 4096 + j0 + j];
        }
        __syncthreads();
#pragma unroll 16
        for (int k = 0; k < 64; ++k) {
            double w = (double)Ws[k * 32 + tx];
            acc0 += Hs[(ty * 2 + 0) * 65 + k] * w;
            acc1 += Hs[(ty * 2 + 1) * 65 + k] * w;
        }
        __syncthreads();
    }
    int col = j0 + tx;
    double c = sqrt(2.0 / M_PI);
    int r0 = ty * 2, r1 = r0 + 1;
    double u0 = acc0 + (double)bfc[col];
    double u1 = acc1 + (double)bfc[col];
    double i0 = c * (u0 + 0.044715 * u0 * u0 * u0);
    double i1 = c * (u1 + 0.044715 * u1 * u1 * u1);
    mb[(size_t)r0 * 4096 + col] = 0.5 * u0 * (1.0 + tanh(i0));
    mb[(size_t)r1 * 4096 + col] = 0.5 * u1 * (1.0 + tanh(i1));
}

// ---- STEP K5: mproj GEMM, k-split 4 -> P4 partials ----
__global__ __launch_bounds__(256) void k_mproj(const double* __restrict__ mb,
        const float* __restrict__ Wmp, double* __restrict__ P4) {
    __shared__ double Hs[16 * 65];
    __shared__ float  Ws[64 * 32];
    int tid = threadIdx.x, tx = tid & 31, ty = tid >> 5;
    int j0 = blockIdx.x * 32;
    int k0 = blockIdx.y * 1024;
    double acc0 = 0, acc1 = 0;
    for (int kc = 0; kc < 1024; kc += 64) {
#pragma unroll
        for (int it = 0; it < 4; ++it) {
            int idx = tid + it * BD; int r = idx >> 6, k = idx & 63;
            Hs[r * 65 + k] = mb[(size_t)r * 4096 + k0 + kc + k];
        }
#pragma unroll
        for (int it = 0; it < 8; ++it) {
            int idx = tid + it * BD; int k = idx >> 5, j = idx & 31;
            Ws[k * 32 + j] = Wmp[(size_t)(k0 + kc + k) * 1024 + j0 + j];
        }
        __syncthreads();
#pragma unroll 16
        for (int k = 0; k < 64; ++k) {
            double w = (double)Ws[k * 32 + tx];
            acc0 += Hs[(ty * 2 + 0) * 65 + k] * w;
            acc1 += Hs[(ty * 2 + 1) * 65 + k] * w;
        }
        __syncthreads();
    }
    int col = j0 + tx;
    int r0 = ty * 2, r1 = r0 + 1;
    P4[((size_t)(blockIdx.y * 16 + r0)) * DIM + col] = acc0;
    P4[((size_t)(blockIdx.y * 16 + r1)) * DIM + col] = acc1;
}

// ---- STEP K6a: x3 = x2 + mproj partials + bias; LNf -> hf ----
__global__ __launch_bounds__(256) void k_lnf(const double* __restrict__ x2, const double* __restrict__ P4,
        const float* __restrict__ bmp, const float* __restrict__ gf, const float* __restrict__ bf,
        double* __restrict__ hf) {
    __shared__ double xs[DIM];
    __shared__ double sc[4];
    int b = blockIdx.x, tid = threadIdx.x;
    for (int i = tid; i < DIM; i += BD) {
        double s = x2[b * DIM + i] + (double)bmp[i];
        for (int ks = 0; ks < 4; ++ks) s += P4[((size_t)(ks * 16 + b)) * DIM + i];
        xs[i] = s;
    }
    __syncthreads();
    double s = 0;
    for (int i = tid; i < DIM; i += BD) s += xs[i];
    s = block_sum(s, sc);
    double m = s * (1.0 / 1024.0);
    double ss = 0;
    for (int i = tid; i < DIM; i += BD) { double d = xs[i] - m; ss += d * d; }
    ss = block_sum(ss, sc);
    double r = 1.0 / sqrt(ss * (1.0 / 1024.0) + 1e-5);
    for (int i = tid; i < DIM; i += BD)
        hf[b * DIM + i] = (xs[i] - m) * r * (double)gf[i] + (double)bf[i];
}

// ---- STEP K6b: score GEMM (W^T) + out write + threshold -> xl ----
__global__ __launch_bounds__(256) void k_score_final(const double* __restrict__ hf,
        const float* __restrict__ Wsc, float* __restrict__ out, double* __restrict__ xl, int t) {
    __shared__ double Hs[16 * 65];
    __shared__ float  Ws[64 * 33];
    int tid = threadIdx.x, tx = tid & 31, ty = tid >> 5;
    int j0 = blockIdx.x * 32;
    double acc0 = 0, acc1 = 0;
    for (int kc = 0; kc < DIM; kc += 64) {
#pragma unroll
        for (int it = 0; it < 4; ++it) {
            int idx = tid + it * BD; int r = idx >> 6, k = idx & 63;
            Hs[r * 65 + k] = hf[r * DIM + kc + k];
        }
#pragma unroll
        for (int it = 0; it < 8; ++it) {
            int idx = tid + it * BD; int j = idx >> 6, k = idx & 63;
            Ws[k * 33 + j] = Wsc[(size_t)(j0 + j) * DIM + kc + k];
        }
        __syncthreads();
#pragma unroll 16
        for (int k = 0; k < 64; ++k) {
            double w = (double)Ws[k * 33 + tx];
            acc0 += Hs[(ty * 2 + 0) * 65 + k] * w;
            acc1 += Hs[(ty * 2 + 1) * 65 + k] * w;
        }
        __syncthreads();
    }
    int col = j0 + tx;
    int r0 = ty * 2, r1 = r0 + 1;
    out[((size_t)r0 * NSTEPS + t) * NPROPS + col] = (float)acc0;
    out[((size_t)r1 * NSTEPS + t) * NPROPS + col] = (float)acc1;
    xl[r0 * DIM + col] = 0.0;
    xl[r1 * DIM + col] = 0.0;
    xl[r0 * DIM + 512 + col] = (acc0 > 0.0) ? 1.0 : 0.0;
    xl[r1 * DIM + 512 + col] = (acc1 > 0.0) ? 1.0 : 0.0;
}

extern "C" void kernel_launch(void* const* d_in, const int* in_sizes, int n_in,
                              void* d_out, int out_size, void* d_ws, size_t ws_size,
                              hipStream_t stream) {
    const int*   tok  = (const int*)d_in[0];
    const float* Wqkv = (const float*)d_in[1];
    const float* bqkv = (const float*)d_in[2];
    const float* Wap  = (const float*)d_in[3];
    const float* bap  = (const float*)d_in[4];
    const float* g1   = (const float*)d_in[5];
    const float* b1   = (const float*)d_in[6];
    const float* g2   = (const float*)d_in[7];
    const float* b2   = (const float*)d_in[8];
    const float* Wfc  = (const float*)d_in[9];
    const float* bfc  = (const float*)d_in[10];
    const float* Wmp  = (const float*)d_in[11];
    const float* bmp  = (const float*)d_in[12];
    const float* gf   = (const float*)d_in[13];
    const float* bf   = (const float*)d_in[14];
    const float* Wsc  = (const float*)d_in[15];
    float* out = (float*)d_out;

    char* w = (char*)d_ws;
    size_t off = 0;
    auto alloc = [&](size_t bytes) -> void* {
        void* p = (void*)(w + off);
        off += (bytes + 255) & ~(size_t)255;
        return p;
    };
    double*      Kc   = (double*)alloc((size_t)NB * SMAX * DIM * 8);
    double*      Vc   = (double*)alloc((size_t)NB * SMAX * DIM * 8);
    double*      mu   = (double*)alloc(4096 * 8);
    double*      rs   = (double*)alloc(4096 * 8);
    double*      xl   = (double*)alloc((size_t)NB * DIM * 8);
    double*      q    = (double*)alloc((size_t)NB * DIM * 8);
    double*      oC   = (double*)alloc((size_t)NB * NCH * DIM * 8);
    double*      mlC  = (double*)alloc((size_t)NB * NCH * 2 * 8);
    double*      ao   = (double*)alloc((size_t)NB * DIM * 8);
    double*      x2   = (double*)alloc((size_t)NB * DIM * 8);
    double*      mb   = (double*)alloc((size_t)NB * 4096 * 8);
    double*      hf   = (double*)alloc((size_t)NB * DIM * 8);
    double*      P4   = (double*)alloc((size_t)4 * NB * DIM * 8);
    signed char* tokc = (signed char*)alloc((size_t)NTOK);
    if (off > ws_size) return;  // fail visibly

    k_tok_convert<<<4096, BD, 0, stream>>>(tok, tokc);
    k_prefix_stats<<<4096, BD, 0, stream>>>(tokc, mu, rs);
    k_init_xl<<<NB, BD, 0, stream>>>(tokc, xl);
    k_prefix<<<dim3(32, 256), BD, 0, stream>>>(tokc, mu, rs, Wqkv, bqkv, g1, b1, Kc, Vc);

    for (int t = 0; t < NSTEPS; ++t) {
        int S = 256 + t, pos = 255 + t;
        k_qkv<<<96, BD, 0, stream>>>(xl, g1, b1, Wqkv, bqkv, q, Kc, Vc, pos);
        k_attn_pv<<<dim3(NB, NCH), BD, 0, stream>>>(q, Kc, Vc, oC, mlC, S);
        k_ao_combine<<<NB, BD, 0, stream>>>(oC, mlC, ao);
        k_aproj<<<32, BD, 0, stream>>>(ao, Wap, bap, xl, x2);
        k_fc<<<128, BD, 0, stream>>>(x2, g2, b2, Wfc, bfc, mb);
        k_mproj<<<dim3(32, 4), BD, 0, stream>>>(mb, Wmp, P4);
        k_lnf<<<NB, BD, 0, stream>>>(x2, P4, bmp, gf, bf, hf);
        k_score_final<<<16, BD, 0, stream>>>(hf, Wsc, out, xl, t);
    }
}

// Round 4
// 11355.711 us; speedup vs baseline: 1.1760x; 1.1760x over previous
//
#include <hip/hip_runtime.h>
#include <math.h>

#ifndef M_PI
#define M_PI 3.14159265358979323846
#endif

#define BD 256
#define NB 16
#define DIM 1024
#define SMAX 288
#define NSTEPS 32
#define NPROPS 512
#define NTOK (16 * 256 * 1024)
#define NCH 9

// counter layout in cnt[] (ints)
#define C1  0    // s1 qkv: 48 j-tiles, n=8
#define C2  64   // s2 attn: 16 batches, n=9
#define C3  96   // s3 aproj: 32 j-tiles, n=8
#define C3B 128  // s3 level-2: n=32
#define C4  160  // s4 fc: 128 j-tiles, n=4
#define C5  320  // s5 mproj: 32 j-tiles, n=16
#define C5B 352  // s5 level-2: n=32
#define C6  384  // s6 score: 16 j-tiles, n=4
#define C6B 416  // s6 level-2: n=16
#define NCNT 512

__device__ __forceinline__ double wred_sum(double v) {
#pragma unroll
    for (int o = 32; o > 0; o >>= 1) v += __shfl_down(v, o, 64);
    return v;
}
__device__ double block_sum(double v, double* sc) {
    v = wred_sum(v);
    int tid = threadIdx.x;
    if ((tid & 63) == 0) sc[tid >> 6] = v;
    __syncthreads();
    double r = sc[0] + sc[1] + sc[2] + sc[3];
    __syncthreads();
    return r;
}
// per-wave LN stats for one row of length DIM -> global mu/rs
__device__ __forceinline__ void wave_ln_stats_g(const double* __restrict__ xrow,
                                                double* mug, double* rsg, int r, int lane) {
    double s = 0;
    for (int i = lane; i < DIM; i += 64) s += xrow[i];
    s = wred_sum(s);
    double m = __shfl(s, 0, 64) * (1.0 / 1024.0);
    double ss = 0;
    for (int i = lane; i < DIM; i += 64) { double d = xrow[i] - m; ss += d * d; }
    ss = wred_sum(ss);
    if (lane == 0) { mug[r] = m; rsg[r] = 1.0 / sqrt(ss * (1.0 / 1024.0) + 1e-5); }
}
// fan-in ticket: returns true for the last-arriving block (all threads uniform)
__device__ __forceinline__ bool ticket(int* c, int n, int* s_old) {
    __threadfence();
    __syncthreads();
    if (threadIdx.x == 0) *s_old = atomicAdd(c, 1);
    __syncthreads();
    bool last = (*s_old == n - 1);
    if (last) __threadfence();
    return last;
}

__global__ __launch_bounds__(256) void k_zero(int* __restrict__ cnt) {
    for (int i = threadIdx.x; i < NCNT; i += BD) cnt[i] = 0;
}

// ---- canonicalize tokens: handles harness passing int32 OR raw int64 ----
__global__ __launch_bounds__(256) void k_tok_convert(const int* __restrict__ tok32,
                                                     signed char* __restrict__ tokc) {
    __shared__ int flag;
    int tid = threadIdx.x;
    if (tid == 0) {
        int nz = 0;
        for (int i = 1; i < 512; i += 2) nz |= tok32[i];
        flag = nz;
    }
    __syncthreads();
    bool is64 = (flag == 0);
#pragma unroll
    for (int it = 0; it < 4; ++it) {
        size_t idx = (size_t)blockIdx.x * 1024 + it * BD + tid;
        int v = is64 ? tok32[2 * idx] : tok32[idx];
        tokc[idx] = (signed char)v;
    }
}

// ---- prefix LN stats ----
__global__ __launch_bounds__(256) void k_prefix_stats(const signed char* __restrict__ tokc,
                                                      double* __restrict__ mu, double* __restrict__ rs) {
    __shared__ double sc[4];
    int T = blockIdx.x, tid = threadIdx.x;
    const signed char* row = tokc + (size_t)T * DIM;
    double s = 0;
    for (int i = tid; i < DIM; i += BD) s += (double)row[i];
    s = block_sum(s, sc);
    double m = s * (1.0 / 1024.0);
    double ss = 0;
    for (int i = tid; i < DIM; i += BD) { double d = (double)row[i] - m; ss += d * d; }
    ss = block_sum(ss, sc);
    if (tid == 0) { mu[T] = m; rs[T] = 1.0 / sqrt(ss * (1.0 / 1024.0) + 1e-5); }
}

// ---- init: xl = last prefix token; ln1 stats for step 0 from prefix stats ----
__global__ __launch_bounds__(256) void k_init(const signed char* __restrict__ tokc,
        const double* __restrict__ mu, const double* __restrict__ rs,
        double* __restrict__ xl, double* __restrict__ mu1, double* __restrict__ rs1) {
    int b = blockIdx.x, tid = threadIdx.x;
    for (int i = tid; i < DIM; i += BD)
        xl[b * DIM + i] = (double)tokc[((size_t)b * 256 + 255) * DIM + i];
    if (tid == 0) { mu1[b] = mu[b * 256 + 255]; rs1[b] = rs[b * 256 + 255]; }
}

// ---- prefix K,V GEMM (unchanged from passing R2 version) ----
__global__ __launch_bounds__(256) void k_prefix(const signed char* __restrict__ tokc,
        const double* __restrict__ mu, const double* __restrict__ rs,
        const float* __restrict__ Wqkv, const float* __restrict__ bqkv,
        const float* __restrict__ g1, const float* __restrict__ b1,
        double* __restrict__ Kc, double* __restrict__ Vc) {
    __shared__ double Hs[64 * 17];
    __shared__ float  Ws[64 * 64];
    int tid = threadIdx.x;
    int tx = tid & 63, ty = tid >> 6;
    int j0 = blockIdx.x * 64;
    int T0 = blockIdx.y * 16;
    double acc[4] = {0, 0, 0, 0};
    for (int kc = 0; kc < DIM; kc += 64) {
#pragma unroll
        for (int it = 0; it < 4; ++it) {
            int idx = tid + it * BD;
            int t = idx & 15, k = idx >> 4;
            int T = T0 + t;
            double x = (double)tokc[(size_t)T * DIM + kc + k];
            Hs[k * 17 + t] = (x - mu[T]) * rs[T] * (double)g1[kc + k] + (double)b1[kc + k];
        }
#pragma unroll
        for (int it = 0; it < 16; ++it) {
            int idx = tid + it * BD;
            int k = idx >> 6, j = idx & 63;
            Ws[k * 64 + j] = Wqkv[(size_t)(kc + k) * 3072 + 1024 + j0 + j];
        }
        __syncthreads();
#pragma unroll 8
        for (int k = 0; k < 64; ++k) {
            double w = (double)Ws[k * 64 + tx];
            acc[0] += Hs[k * 17 + ty * 4 + 0] * w;
            acc[1] += Hs[k * 17 + ty * 4 + 1] * w;
            acc[2] += Hs[k * 17 + ty * 4 + 2] * w;
            acc[3] += Hs[k * 17 + ty * 4 + 3] * w;
        }
        __syncthreads();
    }
    int colg = j0 + tx;
    double bias = (double)bqkv[1024 + colg];
    bool isK = (colg < 1024);
#pragma unroll
    for (int a = 0; a < 4; ++a) {
        int T = T0 + ty * 4 + a;
        int b = T >> 8, pos = T & 255;
        double v = acc[a] + bias;
        if (isK) Kc[((size_t)b * SMAX + pos) * DIM + colg] = v;
        else     Vc[((size_t)b * SMAX + pos) * DIM + colg - 1024] = v;
    }
}

// ---- S1: ln1-from-stats + qkv GEMM (k-split 8, j-tile 64) + ticket combine+scatter ----
__global__ __launch_bounds__(256) void s1_qkv(const double* __restrict__ xl,
        const double* __restrict__ mu1, const double* __restrict__ rs1,
        const float* __restrict__ g1, const float* __restrict__ b1,
        const float* __restrict__ Wqkv, const float* __restrict__ bqkv,
        double* __restrict__ P1, int* __restrict__ cnt,
        double* __restrict__ q, double* __restrict__ Kc, double* __restrict__ Vc, int pos) {
    __shared__ double As[16 * 64];
    __shared__ float  Ws[64 * 64];
    __shared__ int s_old;
    int tid = threadIdx.x, tx = tid & 63, ty = tid >> 6;
    int jt = blockIdx.x, j0 = jt * 64;
    int k0 = blockIdx.y * 128;
    double acc[4] = {0, 0, 0, 0};
    for (int kc = 0; kc < 128; kc += 64) {
#pragma unroll
        for (int it = 0; it < 4; ++it) {
            int idx = tid + it * BD; int r = idx >> 6, k = idx & 63;
            int kg = k0 + kc + k;
            As[r * 64 + k] = (xl[r * DIM + kg] - mu1[r]) * rs1[r] * (double)g1[kg] + (double)b1[kg];
        }
#pragma unroll
        for (int it = 0; it < 16; ++it) {
            int idx = tid + it * BD; int k = idx >> 6, j = idx & 63;
            Ws[k * 64 + j] = Wqkv[(size_t)(k0 + kc + k) * 3072 + j0 + j];
        }
        __syncthreads();
#pragma unroll 8
        for (int k = 0; k < 64; ++k) {
            double w = (double)Ws[k * 64 + tx];
            acc[0] += As[(ty * 4 + 0) * 64 + k] * w;
            acc[1] += As[(ty * 4 + 1) * 64 + k] * w;
            acc[2] += As[(ty * 4 + 2) * 64 + k] * w;
            acc[3] += As[(ty * 4 + 3) * 64 + k] * w;
        }
        __syncthreads();
    }
#pragma unroll
    for (int a = 0; a < 4; ++a)
        P1[((size_t)(blockIdx.y * 16 + ty * 4 + a)) * 3072 + j0 + tx] = acc[a];
    if (!ticket(&cnt[C1 + jt], 8, &s_old)) return;
    // finalize: sum partials + bias, scatter q/K/V
    int col = j0 + tx;
    double bias = (double)bqkv[col];
#pragma unroll
    for (int a = 0; a < 4; ++a) {
        int r = ty * 4 + a;
        double s = bias;
        for (int ks = 0; ks < 8; ++ks) s += P1[((size_t)(ks * 16 + r)) * 3072 + col];
        if (col < 1024)      q[r * DIM + col] = s;
        else if (col < 2048) Kc[((size_t)r * SMAX + pos) * DIM + col - 1024] = s;
        else                 Vc[((size_t)r * SMAX + pos) * DIM + col - 2048] = s;
    }
    if (tid == 0) cnt[C1 + jt] = 0;
}

// ---- S2: chunked scores + local softmax + PV partial + ticket cross-chunk combine ----
__global__ __launch_bounds__(256) void s2_attn(const double* __restrict__ q,
        const double* __restrict__ Kc, const double* __restrict__ Vc,
        double* __restrict__ oC, double* __restrict__ mlC, int* __restrict__ cnt,
        double* __restrict__ ao, int S) {
    __shared__ double qs[DIM];
    __shared__ double ps[32];
    __shared__ int s_old;
    int b = blockIdx.x, c = blockIdx.y, tid = threadIdx.x;
    int lane = tid & 63, w = tid >> 6;
    int pos0 = c * 32;
    for (int i = tid; i < DIM; i += BD) qs[i] = q[b * DIM + i];
    __syncthreads();
    for (int r = 0; r < 8; ++r) {
        int p = w * 8 + r, pos = pos0 + p;
        double d = -1e300;
        if (pos < S) {
            const double* kp = Kc + ((size_t)b * SMAX + pos) * DIM;
            double a = 0;
#pragma unroll
            for (int i = 0; i < 16; ++i) a += qs[lane + 64 * i] * kp[lane + 64 * i];
            a = wred_sum(a);
            d = a * 0.03125;
        }
        if (lane == 0) ps[p] = d;
    }
    __syncthreads();
    int nv = S - pos0;
    if (nv > 32) nv = 32;
    if (nv < 0) nv = 0;
    double m = -1e300, l = 0;
    for (int j = 0; j < 32; ++j) { double v = ps[j]; if (j < nv && v > m) m = v; }
    for (int j = 0; j < 32; ++j) { if (j < nv) l += exp(ps[j] - m); }
    __syncthreads();
    if (tid < 32) ps[tid] = (tid < nv) ? exp(ps[tid] - m) : 0.0;
    __syncthreads();
    double a0 = 0, a1 = 0, a2 = 0, a3 = 0;
    for (int j = 0; j < 32; ++j) {
        double e = ps[j];
        const double* vp = Vc + ((size_t)b * SMAX + pos0 + j) * DIM;
        a0 += e * vp[tid];       a1 += e * vp[tid + 256];
        a2 += e * vp[tid + 512]; a3 += e * vp[tid + 768];
    }
    size_t ob = ((size_t)b * NCH + c) * DIM;
    oC[ob + tid] = a0; oC[ob + tid + 256] = a1;
    oC[ob + tid + 512] = a2; oC[ob + tid + 768] = a3;
    if (tid == 0) { mlC[(b * NCH + c) * 2] = m; mlC[(b * NCH + c) * 2 + 1] = l; }
    if (!ticket(&cnt[C2 + b], NCH, &s_old)) return;
    // finalize: cross-chunk softmax combine -> ao
    double mv[NCH], lv[NCH], wc[NCH];
    double M = -1e300;
    for (int cc = 0; cc < NCH; ++cc) {
        mv[cc] = mlC[(b * NCH + cc) * 2];
        lv[cc] = mlC[(b * NCH + cc) * 2 + 1];
        if (mv[cc] > M) M = mv[cc];
    }
    double den = 0;
    for (int cc = 0; cc < NCH; ++cc) { wc[cc] = exp(mv[cc] - M); den += wc[cc] * lv[cc]; }
    for (int d = tid; d < DIM; d += BD) {
        double s = 0;
        for (int cc = 0; cc < NCH; ++cc) s += wc[cc] * oC[((size_t)b * NCH + cc) * DIM + d];
        ao[b * DIM + d] = s / den;
    }
    if (tid == 0) cnt[C2 + b] = 0;
}

// ---- S3: aproj GEMM (k-split 8, j-tile 32) + ticket (residual->x2) + level-2 ln2 stats ----
__global__ __launch_bounds__(256) void s3_aproj(const double* __restrict__ ao,
        const float* __restrict__ Wap, const float* __restrict__ bap,
        const double* __restrict__ xl, double* __restrict__ P2, int* __restrict__ cnt,
        double* __restrict__ x2, double* __restrict__ mu2, double* __restrict__ rs2) {
    __shared__ double As[16 * 64];
    __shared__ float  Ws[64 * 32];
    __shared__ int s_old;
    int tid = threadIdx.x, tx = tid & 31, ty = tid >> 5;
    int jt = blockIdx.x, j0 = jt * 32;
    int k0 = blockIdx.y * 128;
    double acc0 = 0, acc1 = 0;
    int r0 = ty * 2, r1 = r0 + 1;
    for (int kc = 0; kc < 128; kc += 64) {
#pragma unroll
        for (int it = 0; it < 4; ++it) {
            int idx = tid + it * BD; int r = idx >> 6, k = idx & 63;
            As[r * 64 + k] = ao[r * DIM + k0 + kc + k];
        }
#pragma unroll
        for (int it = 0; it < 8; ++it) {
            int idx = tid + it * BD; int k = idx >> 5, j = idx & 31;
            Ws[k * 32 + j] = Wap[(size_t)(k0 + kc + k) * DIM + j0 + j];
        }
        __syncthreads();
#pragma unroll 16
        for (int k = 0; k < 64; ++k) {
            double w = (double)Ws[k * 32 + tx];
            acc0 += As[r0 * 64 + k] * w;
            acc1 += As[r1 * 64 + k] * w;
        }
        __syncthreads();
    }
    int col = j0 + tx;
    P2[((size_t)(blockIdx.y * 16 + r0)) * DIM + col] = acc0;
    P2[((size_t)(blockIdx.y * 16 + r1)) * DIM + col] = acc1;
    if (!ticket(&cnt[C3 + jt], 8, &s_old)) return;
    double bias = (double)bap[col];
#pragma unroll
    for (int rr = 0; rr < 2; ++rr) {
        int r = ty * 2 + rr;
        double s = bias + xl[r * DIM + col];
        for (int ks = 0; ks < 8; ++ks) s += P2[((size_t)(ks * 16 + r)) * DIM + col];
        x2[r * DIM + col] = s;
    }
    if (tid == 0) cnt[C3 + jt] = 0;
    // level-2: last j-tile computes ln2 stats for all 16 rows
    if (!ticket(&cnt[C3B], 32, &s_old)) return;
    int lane = tid & 63, wv = tid >> 6;
    for (int rr = 0; rr < 4; ++rr) {
        int r = wv * 4 + rr;
        wave_ln_stats_g(x2 + r * DIM, mu2, rs2, r, lane);
    }
    if (tid == 0) cnt[C3B] = 0;
}

// ---- S4: ln2-apply + fc GEMM (k-split 4, j-tile 32) + ticket (bias+gelu->mb) ----
__global__ __launch_bounds__(256) void s4_fc(const double* __restrict__ x2,
        const double* __restrict__ mu2, const double* __restrict__ rs2,
        const float* __restrict__ g2, const float* __restrict__ b2,
        const float* __restrict__ Wfc, const float* __restrict__ bfc,
        double* __restrict__ P3, int* __restrict__ cnt, double* __restrict__ mb) {
    __shared__ double As[16 * 64];
    __shared__ float  Ws[64 * 32];
    __shared__ int s_old;
    int tid = threadIdx.x, tx = tid & 31, ty = tid >> 5;
    int jt = blockIdx.x, j0 = jt * 32;
    int k0 = blockIdx.y * 256;
    double acc0 = 0, acc1 = 0;
    int r0 = ty * 2, r1 = r0 + 1;
    for (int kc = 0; kc < 256; kc += 64) {
#pragma unroll
        for (int it = 0; it < 4; ++it) {
            int idx = tid + it * BD; int r = idx >> 6, k = idx & 63;
            int kg = k0 + kc + k;
            As[r * 64 + k] = (x2[r * DIM + kg] - mu2[r]) * rs2[r] * (double)g2[kg] + (double)b2[kg];
        }
#pragma unroll
        for (int it = 0; it < 8; ++it) {
            int idx = tid + it * BD; int k = idx >> 5, j = idx & 31;
            Ws[k * 32 + j] = Wfc[(size_t)(k0 + kc + k) * 4096 + j0 + j];
        }
        __syncthreads();
#pragma unroll 16
        for (int k = 0; k < 64; ++k) {
            double w = (double)Ws[k * 32 + tx];
            acc0 += As[r0 * 64 + k] * w;
            acc1 += As[r1 * 64 + k] * w;
        }
        __syncthreads();
    }
    int col = j0 + tx;
    P3[((size_t)(blockIdx.y * 16 + r0)) * 4096 + col] = acc0;
    P3[((size_t)(blockIdx.y * 16 + r1)) * 4096 + col] = acc1;
    if (!ticket(&cnt[C4 + jt], 4, &s_old)) return;
    double bias = (double)bfc[col];
    double cgel = sqrt(2.0 / M_PI);
#pragma unroll
    for (int rr = 0; rr < 2; ++rr) {
        int r = ty * 2 + rr;
        double u = bias;
        for (int ks = 0; ks < 4; ++ks) u += P3[((size_t)(ks * 16 + r)) * 4096 + col];
        double inner = cgel * (u + 0.044715 * u * u * u);
        mb[(size_t)r * 4096 + col] = 0.5 * u * (1.0 + tanh(inner));
    }
    if (tid == 0) cnt[C4 + jt] = 0;
}

// ---- S5: mproj GEMM (k-split 16, j-tile 32) + ticket (residual->x3) + level-2 lnf stats ----
__global__ __launch_bounds__(256) void s5_mproj(const double* __restrict__ mb,
        const float* __restrict__ Wmp, const float* __restrict__ bmp,
        const double* __restrict__ x2, double* __restrict__ P4, int* __restrict__ cnt,
        double* __restrict__ x3, double* __restrict__ muf, double* __restrict__ rsf) {
    __shared__ double As[16 * 64];
    __shared__ float  Ws[64 * 32];
    __shared__ int s_old;
    int tid = threadIdx.x, tx = tid & 31, ty = tid >> 5;
    int jt = blockIdx.x, j0 = jt * 32;
    int k0 = blockIdx.y * 256;
    double acc0 = 0, acc1 = 0;
    int r0 = ty * 2, r1 = r0 + 1;
    for (int kc = 0; kc < 256; kc += 64) {
#pragma unroll
        for (int it = 0; it < 4; ++it) {
            int idx = tid + it * BD; int r = idx >> 6, k = idx & 63;
            As[r * 64 + k] = mb[(size_t)r * 4096 + k0 + kc + k];
        }
#pragma unroll
        for (int it = 0; it < 8; ++it) {
            int idx = tid + it * BD; int k = idx >> 5, j = idx & 31;
            Ws[k * 32 + j] = Wmp[(size_t)(k0 + kc + k) * DIM + j0 + j];
        }
        __syncthreads();
#pragma unroll 16
        for (int k = 0; k < 64; ++k) {
            double w = (double)Ws[k * 32 + tx];
            acc0 += As[r0 * 64 + k] * w;
            acc1 += As[r1 * 64 + k] * w;
        }
        __syncthreads();
    }
    int col = j0 + tx;
    P4[((size_t)(blockIdx.y * 16 + r0)) * DIM + col] = acc0;
    P4[((size_t)(blockIdx.y * 16 + r1)) * DIM + col] = acc1;
    if (!ticket(&cnt[C5 + jt], 16, &s_old)) return;
    double bias = (double)bmp[col];
#pragma unroll
    for (int rr = 0; rr < 2; ++rr) {
        int r = ty * 2 + rr;
        double s = bias + x2[r * DIM + col];
        for (int ks = 0; ks < 16; ++ks) s += P4[((size_t)(ks * 16 + r)) * DIM + col];
        x3[r * DIM + col] = s;
    }
    if (tid == 0) cnt[C5 + jt] = 0;
    if (!ticket(&cnt[C5B], 32, &s_old)) return;
    int lane = tid & 63, wv = tid >> 6;
    for (int rr = 0; rr < 4; ++rr) {
        int r = wv * 4 + rr;
        wave_ln_stats_g(x3 + r * DIM, muf, rsf, r, lane);
    }
    if (tid == 0) cnt[C5B] = 0;
}

// ---- S6: lnf-apply + score GEMM W^T (k-split 4, j-tile 32) + ticket (out+threshold+bits)
//      + level-2: closed-form ln1 stats for next step ----
__global__ __launch_bounds__(256) void s6_score(const double* __restrict__ x3,
        const double* __restrict__ muf, const double* __restrict__ rsf,
        const float* __restrict__ gf, const float* __restrict__ bf,
        const float* __restrict__ Wsc, double* __restrict__ P5, int* __restrict__ cnt,
        float* __restrict__ out, double* __restrict__ xl,
        double* __restrict__ mu1, double* __restrict__ rs1, int t) {
    __shared__ double As[16 * 64];
    __shared__ float  Ws[64 * 33];
    __shared__ int s_old;
    int tid = threadIdx.x, tx = tid & 31, ty = tid >> 5;
    int jt = blockIdx.x, j0 = jt * 32;
    int k0 = blockIdx.y * 256;
    double acc0 = 0, acc1 = 0;
    int r0 = ty * 2, r1 = r0 + 1;
    for (int kc = 0; kc < 256; kc += 64) {
#pragma unroll
        for (int it = 0; it < 4; ++it) {
            int idx = tid + it * BD; int r = idx >> 6, k = idx & 63;
            int kg = k0 + kc + k;
            As[r * 64 + k] = (x3[r * DIM + kg] - muf[r]) * rsf[r] * (double)gf[kg] + (double)bf[kg];
        }
#pragma unroll
        for (int it = 0; it < 8; ++it) {
            int idx = tid + it * BD; int j = idx >> 6, k = idx & 63;
            Ws[k * 33 + j] = Wsc[(size_t)(j0 + j) * DIM + k0 + kc + k];
        }
        __syncthreads();
#pragma unroll 16
        for (int k = 0; k < 64; ++k) {
            double w = (double)Ws[k * 33 + tx];
            acc0 += As[r0 * 64 + k] * w;
            acc1 += As[r1 * 64 + k] * w;
        }
        __syncthreads();
    }
    int col = j0 + tx;
    P5[((size_t)(blockIdx.y * 16 + r0)) * NPROPS + col] = acc0;
    P5[((size_t)(blockIdx.y * 16 + r1)) * NPROPS + col] = acc1;
    if (!ticket(&cnt[C6 + jt], 4, &s_old)) return;
#pragma unroll
    for (int rr = 0; rr < 2; ++rr) {
        int r = ty * 2 + rr;
        double lg = 0;
        for (int ks = 0; ks < 4; ++ks) lg += P5[((size_t)(ks * 16 + r)) * NPROPS + col];
        out[((size_t)r * NSTEPS + t) * NPROPS + col] = (float)lg;
        xl[r * DIM + col] = 0.0;
        xl[r * DIM + 512 + col] = (lg > 0.0) ? 1.0 : 0.0;
    }
    if (tid == 0) cnt[C6 + jt] = 0;
    // level-2: closed-form ln1 stats of [0^512, bits] from popcount
    if (!ticket(&cnt[C6B], 16, &s_old)) return;
    int lane = tid & 63, wv = tid >> 6;
    for (int rr = 0; rr < 4; ++rr) {
        int r = wv * 4 + rr;
        double s = 0;
        for (int i = lane; i < 512; i += 64) s += xl[r * DIM + 512 + i];
        s = wred_sum(s);
        if (lane == 0) {
            double nb = s;
            double m = nb * (1.0 / 1024.0);
            double var = ((1024.0 - nb) * m * m + nb * (1.0 - m) * (1.0 - m)) * (1.0 / 1024.0);
            mu1[r] = m;
            rs1[r] = 1.0 / sqrt(var + 1e-5);
        }
    }
    if (tid == 0) cnt[C6B] = 0;
}

extern "C" void kernel_launch(void* const* d_in, const int* in_sizes, int n_in,
                              void* d_out, int out_size, void* d_ws, size_t ws_size,
                              hipStream_t stream) {
    const int*   tok  = (const int*)d_in[0];
    const float* Wqkv = (const float*)d_in[1];
    const float* bqkv = (const float*)d_in[2];
    const float* Wap  = (const float*)d_in[3];
    const float* bap  = (const float*)d_in[4];
    const float* g1   = (const float*)d_in[5];
    const float* b1   = (const float*)d_in[6];
    const float* g2   = (const float*)d_in[7];
    const float* b2   = (const float*)d_in[8];
    const float* Wfc  = (const float*)d_in[9];
    const float* bfc  = (const float*)d_in[10];
    const float* Wmp  = (const float*)d_in[11];
    const float* bmp  = (const float*)d_in[12];
    const float* gf   = (const float*)d_in[13];
    const float* bf   = (const float*)d_in[14];
    const float* Wsc  = (const float*)d_in[15];
    float* out = (float*)d_out;

    char* w = (char*)d_ws;
    size_t off = 0;
    auto alloc = [&](size_t bytes) -> void* {
        void* p = (void*)(w + off);
        off += (bytes + 255) & ~(size_t)255;
        return p;
    };
    double*      Kc   = (double*)alloc((size_t)NB * SMAX * DIM * 8);
    double*      Vc   = (double*)alloc((size_t)NB * SMAX * DIM * 8);
    double*      mu   = (double*)alloc(4096 * 8);
    double*      rs   = (double*)alloc(4096 * 8);
    double*      xl   = (double*)alloc((size_t)NB * DIM * 8);
    double*      q    = (double*)alloc((size_t)NB * DIM * 8);
    double*      oC   = (double*)alloc((size_t)NB * NCH * DIM * 8);
    double*      mlC  = (double*)alloc((size_t)NB * NCH * 2 * 8);
    double*      ao   = (double*)alloc((size_t)NB * DIM * 8);
    double*      x2   = (double*)alloc((size_t)NB * DIM * 8);
    double*      x3   = (double*)alloc((size_t)NB * DIM * 8);
    double*      mb   = (double*)alloc((size_t)NB * 4096 * 8);
    double*      P1   = (double*)alloc((size_t)8 * NB * 3072 * 8);
    double*      P2   = (double*)alloc((size_t)8 * NB * DIM * 8);
    double*      P3   = (double*)alloc((size_t)4 * NB * 4096 * 8);
    double*      P4   = (double*)alloc((size_t)16 * NB * DIM * 8);
    double*      P5   = (double*)alloc((size_t)4 * NB * NPROPS * 8);
    double*      mu1  = (double*)alloc(NB * 8);
    double*      rs1  = (double*)alloc(NB * 8);
    double*      mu2  = (double*)alloc(NB * 8);
    double*      rs2  = (double*)alloc(NB * 8);
    double*      muf  = (double*)alloc(NB * 8);
    double*      rsf  = (double*)alloc(NB * 8);
    int*         cnt  = (int*)alloc(NCNT * 4);
    signed char* tokc = (signed char*)alloc((size_t)NTOK);
    if (off > ws_size) return;  // fail visibly

    k_zero<<<1, BD, 0, stream>>>(cnt);
    k_tok_convert<<<4096, BD, 0, stream>>>(tok, tokc);
    k_prefix_stats<<<4096, BD, 0, stream>>>(tokc, mu, rs);
    k_init<<<NB, BD, 0, stream>>>(tokc, mu, rs, xl, mu1, rs1);
    k_prefix<<<dim3(32, 256), BD, 0, stream>>>(tokc, mu, rs, Wqkv, bqkv, g1, b1, Kc, Vc);

    for (int t = 0; t < NSTEPS; ++t) {
        int S = 256 + t, pos = 255 + t;
        s1_qkv<<<dim3(48, 8), BD, 0, stream>>>(xl, mu1, rs1, g1, b1, Wqkv, bqkv, P1, cnt, q, Kc, Vc, pos);
        s2_attn<<<dim3(NB, NCH), BD, 0, stream>>>(q, Kc, Vc, oC, mlC, cnt, ao, S);
        s3_aproj<<<dim3(32, 8), BD, 0, stream>>>(ao, Wap, bap, xl, P2, cnt, x2, mu2, rs2);
        s4_fc<<<dim3(128, 4), BD, 0, stream>>>(x2, mu2, rs2, g2, b2, Wfc, bfc, P3, cnt, mb);
        s5_mproj<<<dim3(32, 16), BD, 0, stream>>>(mb, Wmp, bmp, x2, P4, cnt, x3, muf, rsf);
        s6_score<<<dim3(16, 4), BD, 0, stream>>>(x3, muf, rsf, gf, bf, Wsc, P5, cnt, out, xl, mu1, rs1, t);
    }
}

// Round 5
// 7055.254 us; speedup vs baseline: 1.8929x; 1.6095x over previous
//
#include <hip/hip_runtime.h>
#include <math.h>

#ifndef M_PI
#define M_PI 3.14159265358979323846
#endif

#define BD 256
#define NB 16
#define DIM 1024
#define SMAX 288
#define NSTEPS 32
#define NPROPS 512
#define NTOK (16 * 256 * 1024)
#define XW 16   // u64 words per token row

__device__ __forceinline__ double wred_sum(double v) {
#pragma unroll
    for (int o = 32; o > 0; o >>= 1) v += __shfl_down(v, o, 64);
    return v;
}
__device__ __forceinline__ double wred_max(double v) {
#pragma unroll
    for (int o = 32; o > 0; o >>= 1) { double w = __shfl_down(v, o, 64); if (w > v) v = w; }
    return v;
}
__device__ double block_sum(double v, double* sc) {
    v = wred_sum(v);
    int tid = threadIdx.x;
    if ((tid & 63) == 0) sc[tid >> 6] = v;
    __syncthreads();
    double r = sc[0] + sc[1] + sc[2] + sc[3];
    __syncthreads();
    return r;
}
__device__ double block_max(double v, double* sc) {
    v = wred_max(v);
    int tid = threadIdx.x;
    if ((tid & 63) == 0) sc[tid >> 6] = v;
    __syncthreads();
    double r = fmax(fmax(sc[0], sc[1]), fmax(sc[2], sc[3]));
    __syncthreads();
    return r;
}

// ---- canonicalize tokens: handles harness passing int32 OR raw int64 ----
__global__ __launch_bounds__(256) void k_tok_convert(const int* __restrict__ tok32,
                                                     signed char* __restrict__ tokc) {
    __shared__ int flag;
    int tid = threadIdx.x;
    if (tid == 0) {
        int nz = 0;
        for (int i = 1; i < 512; i += 2) nz |= tok32[i];
        flag = nz;
    }
    __syncthreads();
    bool is64 = (flag == 0);
#pragma unroll
    for (int it = 0; it < 4; ++it) {
        size_t idx = (size_t)blockIdx.x * 1024 + it * BD + tid;
        int v = is64 ? tok32[2 * idx] : tok32[idx];
        tokc[idx] = (signed char)v;
    }
}

// ---- pack prefix tokens into bitmasks: X[(b*SMAX+pos)*16 + w] ----
__global__ __launch_bounds__(256) void k_pack(const signed char* __restrict__ tokc,
                                              unsigned long long* __restrict__ X) {
    int tid = threadIdx.x, lane = tid & 63, wv = tid >> 6;
    int T = blockIdx.x * 4 + wv;  // 0..4095
    int b = T >> 8, pos = T & 255;
    for (int w = 0; w < XW; ++w) {
        signed char byte = tokc[(size_t)T * DIM + w * 64 + lane];
        unsigned long long m = __ballot(byte != 0);
        if (lane == 0) X[((size_t)b * SMAX + pos) * XW + w] = m;
    }
}

// ---- closed-form LN stats per prefix token from popcount (exact for 0/1 rows) ----
__global__ __launch_bounds__(256) void k_posstats(const unsigned long long* __restrict__ X,
        double* __restrict__ mu_pos, double* __restrict__ rs_pos) {
    int T = blockIdx.x * BD + threadIdx.x;  // 0..4095
    int b = T >> 8, pos = T & 255;
    const unsigned long long* xw = X + ((size_t)b * SMAX + pos) * XW;
    int nbi = 0;
    for (int w = 0; w < XW; ++w) nbi += __popcll(xw[w]);
    double nb = (double)nbi;
    double m = nb * (1.0 / 1024.0);
    double var = ((1024.0 - nb) * m * m + nb * (1.0 - m) * (1.0 - m)) * (1.0 / 1024.0);
    mu_pos[b * SMAX + pos] = m;
    rs_pos[b * SMAX + pos] = 1.0 / sqrt(var + 1e-5);
}

// ---- xl = embedding of last prefix token ----
__global__ __launch_bounds__(256) void k_init(const signed char* __restrict__ tokc,
                                              double* __restrict__ xl) {
    int b = blockIdx.x, tid = threadIdx.x;
    for (int i = tid; i < DIM; i += BD)
        xl[b * DIM + i] = (double)tokc[((size_t)b * 256 + 255) * DIM + i];
}

// ---- precompute G_K[j]=sum_k g1[k]*Wk[k,j], KB[j]=sum_k b1[k]*Wk[k,j]+bk[j]; same for V ----
__global__ __launch_bounds__(256) void k_precomp(const float* __restrict__ Wqkv,
        const float* __restrict__ bqkv, const float* __restrict__ g1, const float* __restrict__ b1,
        double* __restrict__ G_K, double* __restrict__ KB,
        double* __restrict__ Gv, double* __restrict__ VB) {
    __shared__ double rg[256], rb[256];
    int tid = threadIdx.x;
    int sec = blockIdx.x >> 4;          // 0 = K section, 1 = V section
    int jt = blockIdx.x & 15;
    int j = jt * 64 + (tid & 63);
    int kp = tid >> 6;                  // 4 k-partitions of 256
    double ag = 0, ab = 0;
    int cbase = 1024 + sec * 1024 + j;
    for (int k = kp * 256; k < kp * 256 + 256; ++k) {
        double w = (double)Wqkv[(size_t)k * 3072 + cbase];
        ag += (double)g1[k] * w;
        ab += (double)b1[k] * w;
    }
    rg[tid] = ag; rb[tid] = ab;
    __syncthreads();
    if (tid < 64) {
        double sg = ((rg[tid] + rg[tid + 64]) + (rg[tid + 128] + rg[tid + 192]));
        double sb = ((rb[tid] + rb[tid + 64]) + (rb[tid + 128] + rb[tid + 192]));
        double bias = (double)bqkv[cbase];
        if (sec == 0) { G_K[j] = sg; KB[j] = sb + bias; }
        else          { Gv[j]  = sg; VB[j] = sb + bias; }
    }
}

// ---- S1: q GEMM with LN1-from-stats in A-stage (k-split 8, j-tile 64) -> Pq partials ----
__global__ __launch_bounds__(256) void k_q(const double* __restrict__ xl,
        const double* __restrict__ mu_pos, const double* __restrict__ rs_pos, int posq,
        const float* __restrict__ g1, const float* __restrict__ b1,
        const float* __restrict__ Wqkv, double* __restrict__ Pq) {
    __shared__ double As[16 * 64];
    __shared__ float  Ws[64 * 64];
    int tid = threadIdx.x, tx = tid & 63, ty = tid >> 6;
    int j0 = blockIdx.x * 64;
    int k0 = blockIdx.y * 128;
    double acc[4] = {0, 0, 0, 0};
    for (int kc = 0; kc < 128; kc += 64) {
#pragma unroll
        for (int it = 0; it < 4; ++it) {
            int idx = tid + it * BD; int r = idx >> 6, k = idx & 63;
            int kg = k0 + kc + k;
            double m = mu_pos[r * SMAX + posq], rsv = rs_pos[r * SMAX + posq];
            As[r * 64 + k] = (xl[r * DIM + kg] - m) * rsv * (double)g1[kg] + (double)b1[kg];
        }
#pragma unroll
        for (int it = 0; it < 16; ++it) {
            int idx = tid + it * BD; int k = idx >> 6, j = idx & 63;
            Ws[k * 64 + j] = Wqkv[(size_t)(k0 + kc + k) * 3072 + j0 + j];
        }
        __syncthreads();
#pragma unroll 8
        for (int k = 0; k < 64; ++k) {
            double w = (double)Ws[k * 64 + tx];
            acc[0] += As[(ty * 4 + 0) * 64 + k] * w;
            acc[1] += As[(ty * 4 + 1) * 64 + k] * w;
            acc[2] += As[(ty * 4 + 2) * 64 + k] * w;
            acc[3] += As[(ty * 4 + 3) * 64 + k] * w;
        }
        __syncthreads();
    }
#pragma unroll
    for (int a = 0; a < 4; ++a)
        Pq[((size_t)(blockIdx.y * 16 + ty * 4 + a)) * DIM + j0 + tx] = acc[a];
}

// ---- S2: u GEMM: u[b,ko] = sum_j Wk[ko,j]*q[b,j] (fold Pq+bias), transposed-W -> Pu ----
__global__ __launch_bounds__(256) void k_u(const double* __restrict__ Pq,
        const float* __restrict__ bqkv, const float* __restrict__ Wqkv,
        double* __restrict__ Pu) {
    __shared__ double As[16 * 64];
    __shared__ float  Ws[64 * 65];
    int tid = threadIdx.x, tx = tid & 63, ty = tid >> 6;
    int j0 = blockIdx.x * 64;          // out-k tile
    int k0 = blockIdx.y * 128;         // reduction (q-dim) slice
    double acc[4] = {0, 0, 0, 0};
    for (int kc = 0; kc < 128; kc += 64) {
#pragma unroll
        for (int it = 0; it < 4; ++it) {
            int idx = tid + it * BD; int r = idx >> 6, k = idx & 63;
            int jg = k0 + kc + k;
            double s = (double)bqkv[jg];
            for (int ks = 0; ks < 8; ++ks) s += Pq[((size_t)(ks * 16 + r)) * DIM + jg];
            As[r * 64 + k] = s;
        }
#pragma unroll
        for (int it = 0; it < 16; ++it) {
            int idx = tid + it * BD; int j = idx >> 6, k = idx & 63;
            // Wk[ko, jred] = Wqkv[ko*3072 + 1024 + jred]
            Ws[k * 65 + j] = Wqkv[(size_t)(j0 + j) * 3072 + 1024 + k0 + kc + k];
        }
        __syncthreads();
#pragma unroll 8
        for (int k = 0; k < 64; ++k) {
            double w = (double)Ws[k * 65 + tx];
            acc[0] += As[(ty * 4 + 0) * 64 + k] * w;
            acc[1] += As[(ty * 4 + 1) * 64 + k] * w;
            acc[2] += As[(ty * 4 + 2) * 64 + k] * w;
            acc[3] += As[(ty * 4 + 3) * 64 + k] * w;
        }
        __syncthreads();
    }
#pragma unroll
    for (int a = 0; a < 4; ++a)
        Pu[((size_t)(blockIdx.y * 16 + ty * 4 + a)) * DIM + j0 + tx] = acc[a];
}

// ---- S3: per-batch attention via bitmask selection: scores, softmax, c2, alpha ----
__global__ __launch_bounds__(256) void k_attn(const double* __restrict__ Pq,
        const double* __restrict__ Pu, const float* __restrict__ bqkv,
        const float* __restrict__ g1, const double* __restrict__ G_K, const double* __restrict__ KB,
        const unsigned long long* __restrict__ X,
        const double* __restrict__ mu_pos, const double* __restrict__ rs_pos,
        double* __restrict__ c2, double* __restrict__ alpha, int S) {
    __shared__ double u_s[DIM];                    // 8 KB
    __shared__ unsigned long long X_s[SMAX * XW];  // 36 KB
    __shared__ double w_s[SMAX];
    __shared__ double sc[4];
    int b = blockIdx.x, tid = threadIdx.x;
    // u = g1 * (sum of Pu partials)
    for (int k = tid; k < DIM; k += BD) {
        double s = 0;
        for (int ks = 0; ks < 8; ++ks) s += Pu[((size_t)(ks * 16 + b)) * DIM + k];
        u_s[k] = (double)g1[k] * s;
    }
    // stage bitmasks
    for (int i = tid; i < S * XW; i += BD) X_s[i] = X[(size_t)b * SMAX * XW + i];
    // qG, qKB (fold Pq + bias on the fly)
    double qg = 0, qkb = 0;
    for (int j = tid; j < DIM; j += BD) {
        double q = (double)bqkv[j];
        for (int ks = 0; ks < 8; ++ks) q += Pq[((size_t)(ks * 16 + b)) * DIM + j];
        qg += q * G_K[j];
        qkb += q * KB[j];
    }
    qg = block_sum(qg, sc);
    qkb = block_sum(qkb, sc);
    __syncthreads();
    // scores (2 positions per thread)
    double sv[2] = {-1e300, -1e300};
#pragma unroll
    for (int r = 0; r < 2; ++r) {
        int pos = tid + r * BD;
        if (pos < S) {
            double sel = 0;
            for (int w = 0; w < XW; ++w) {
                unsigned long long m = X_s[pos * XW + w];
                while (m) {
                    int i = __ffsll((long long)m) - 1;
                    sel += u_s[w * 64 + i];
                    m &= m - 1;
                }
            }
            double rp = rs_pos[b * SMAX + pos], mp = mu_pos[b * SMAX + pos];
            sv[r] = (rp * sel - rp * mp * qg + qkb) * 0.03125;
        }
    }
    double M = block_max(fmax(sv[0], sv[1]), sc);
    double den = 0, ah = 0;
#pragma unroll
    for (int r = 0; r < 2; ++r) {
        int pos = tid + r * BD;
        if (pos < S) {
            double e = exp(sv[r] - M);
            double rp = rs_pos[b * SMAX + pos], mp = mu_pos[b * SMAX + pos];
            den += e;
            ah -= e * rp * mp;
            w_s[pos] = e * rp;
        }
    }
    den = block_sum(den, sc);
    ah = block_sum(ah, sc);
    __syncthreads();
    // c2[b,k] = g1[k] * (sum_pos w_s[pos] * bit(pos,k)) / den
#pragma unroll
    for (int r = 0; r < 4; ++r) {
        int k = tid + r * BD;
        int w = k >> 6, bit = k & 63;
        double cc = 0;
        for (int pos = 0; pos < S; ++pos) {
            unsigned long long xw = X_s[pos * XW + w];
            cc += ((xw >> bit) & 1ull) ? w_s[pos] : 0.0;
        }
        c2[b * DIM + k] = (double)g1[k] * cc / den;
    }
    if (tid == 0) alpha[b] = ah / den;
}

// ---- S4: ao GEMM: Pv = c2 @ Wv (+ alpha*Gv + VB added by ks==0) ----
__global__ __launch_bounds__(256) void k_v(const double* __restrict__ c2,
        const float* __restrict__ Wqkv, const double* __restrict__ Gv, const double* __restrict__ VB,
        const double* __restrict__ alpha, double* __restrict__ Pv) {
    __shared__ double As[16 * 64];
    __shared__ float  Ws[64 * 64];
    int tid = threadIdx.x, tx = tid & 63, ty = tid >> 6;
    int j0 = blockIdx.x * 64;
    int k0 = blockIdx.y * 128;
    double acc[4] = {0, 0, 0, 0};
    for (int kc = 0; kc < 128; kc += 64) {
#pragma unroll
        for (int it = 0; it < 4; ++it) {
            int idx = tid + it * BD; int r = idx >> 6, k = idx & 63;
            As[r * 64 + k] = c2[r * DIM + k0 + kc + k];
        }
#pragma unroll
        for (int it = 0; it < 16; ++it) {
            int idx = tid + it * BD; int k = idx >> 6, j = idx & 63;
            Ws[k * 64 + j] = Wqkv[(size_t)(k0 + kc + k) * 3072 + 2048 + j0 + j];
        }
        __syncthreads();
#pragma unroll 8
        for (int k = 0; k < 64; ++k) {
            double w = (double)Ws[k * 64 + tx];
            acc[0] += As[(ty * 4 + 0) * 64 + k] * w;
            acc[1] += As[(ty * 4 + 1) * 64 + k] * w;
            acc[2] += As[(ty * 4 + 2) * 64 + k] * w;
            acc[3] += As[(ty * 4 + 3) * 64 + k] * w;
        }
        __syncthreads();
    }
    int col = j0 + tx;
#pragma unroll
    for (int a = 0; a < 4; ++a) {
        int r = ty * 4 + a;
        double base = (blockIdx.y == 0) ? (alpha[r] * Gv[col] + VB[col]) : 0.0;
        Pv[((size_t)(blockIdx.y * 16 + r)) * DIM + col] = acc[a] + base;
    }
}

// ---- S5: aproj GEMM with A-fold of Pv -> P2 partials ----
__global__ __launch_bounds__(256) void k_aproj(const double* __restrict__ Pv,
        const float* __restrict__ Wap, double* __restrict__ P2) {
    __shared__ double As[16 * 64];
    __shared__ float  Ws[64 * 64];
    int tid = threadIdx.x, tx = tid & 63, ty = tid >> 6;
    int j0 = blockIdx.x * 64;
    int k0 = blockIdx.y * 128;
    double acc[4] = {0, 0, 0, 0};
    for (int kc = 0; kc < 128; kc += 64) {
#pragma unroll
        for (int it = 0; it < 4; ++it) {
            int idx = tid + it * BD; int r = idx >> 6, k = idx & 63;
            int kg = k0 + kc + k;
            double s = 0;
            for (int ks = 0; ks < 8; ++ks) s += Pv[((size_t)(ks * 16 + r)) * DIM + kg];
            As[r * 64 + k] = s;
        }
#pragma unroll
        for (int it = 0; it < 16; ++it) {
            int idx = tid + it * BD; int k = idx >> 6, j = idx & 63;
            Ws[k * 64 + j] = Wap[(size_t)(k0 + kc + k) * DIM + j0 + j];
        }
        __syncthreads();
#pragma unroll 8
        for (int k = 0; k < 64; ++k) {
            double w = (double)Ws[k * 64 + tx];
            acc[0] += As[(ty * 4 + 0) * 64 + k] * w;
            acc[1] += As[(ty * 4 + 1) * 64 + k] * w;
            acc[2] += As[(ty * 4 + 2) * 64 + k] * w;
            acc[3] += As[(ty * 4 + 3) * 64 + k] * w;
        }
        __syncthreads();
    }
#pragma unroll
    for (int a = 0; a < 4; ++a)
        P2[((size_t)(blockIdx.y * 16 + ty * 4 + a)) * DIM + j0 + tx] = acc[a];
}

// ---- generic 16-row GEMM (R2-proven): P[ky][b][col] = sum_k A[b][k]*W[k][col] ----
__global__ __launch_bounds__(256) void mm16(const double* __restrict__ A, int K,
        const float* __restrict__ W, int ldw, double* __restrict__ P, int ncols) {
    __shared__ double As[16 * 64];
    __shared__ float  Ws[64 * 64];
    int tid = threadIdx.x, tx = tid & 63, ty = tid >> 6;
    int j0 = blockIdx.x * 64;
    int klen = K / gridDim.y;
    int k0 = blockIdx.y * klen;
    double acc[4] = {0, 0, 0, 0};
    for (int kc = 0; kc < klen; kc += 64) {
#pragma unroll
        for (int it = 0; it < 4; ++it) {
            int idx = tid + it * BD;
            int b = idx >> 6, k = idx & 63;
            As[b * 64 + k] = A[(size_t)b * K + k0 + kc + k];
        }
#pragma unroll
        for (int it = 0; it < 16; ++it) {
            int idx = tid + it * BD;
            int k = idx >> 6, j = idx & 63;
            Ws[k * 64 + j] = W[(size_t)(k0 + kc + k) * ldw + j0 + j];
        }
        __syncthreads();
#pragma unroll 8
        for (int k = 0; k < 64; ++k) {
            double w = (double)Ws[k * 64 + tx];
            acc[0] += As[(ty * 4 + 0) * 64 + k] * w;
            acc[1] += As[(ty * 4 + 1) * 64 + k] * w;
            acc[2] += As[(ty * 4 + 2) * 64 + k] * w;
            acc[3] += As[(ty * 4 + 3) * 64 + k] * w;
        }
        __syncthreads();
    }
#pragma unroll
    for (int a = 0; a < 4; ++a)
        P[((size_t)(blockIdx.y * 16 + ty * 4 + a)) * ncols + j0 + tx] = acc[a];
}

// ---- transposed-W variant (R2-proven) ----
__global__ __launch_bounds__(256) void mm16_t(const double* __restrict__ A, int K,
        const float* __restrict__ Wt, double* __restrict__ P, int ncols) {
    __shared__ double As[16 * 64];
    __shared__ float  Ws[64 * 65];
    int tid = threadIdx.x, tx = tid & 63, ty = tid >> 6;
    int j0 = blockIdx.x * 64;
    int klen = K / gridDim.y;
    int k0 = blockIdx.y * klen;
    double acc[4] = {0, 0, 0, 0};
    for (int kc = 0; kc < klen; kc += 64) {
#pragma unroll
        for (int it = 0; it < 4; ++it) {
            int idx = tid + it * BD;
            int b = idx >> 6, k = idx & 63;
            As[b * 64 + k] = A[(size_t)b * K + k0 + kc + k];
        }
#pragma unroll
        for (int it = 0; it < 16; ++it) {
            int idx = tid + it * BD;
            int j = idx >> 6, k = idx & 63;
            Ws[k * 65 + j] = Wt[(size_t)(j0 + j) * K + k0 + kc + k];
        }
        __syncthreads();
#pragma unroll 8
        for (int k = 0; k < 64; ++k) {
            double w = (double)Ws[k * 65 + tx];
            acc[0] += As[(ty * 4 + 0) * 64 + k] * w;
            acc[1] += As[(ty * 4 + 1) * 64 + k] * w;
            acc[2] += As[(ty * 4 + 2) * 64 + k] * w;
            acc[3] += As[(ty * 4 + 3) * 64 + k] * w;
        }
        __syncthreads();
    }
#pragma unroll
    for (int a = 0; a < 4; ++a)
        P[((size_t)(blockIdx.y * 16 + ty * 4 + a)) * ncols + j0 + tx] = acc[a];
}

// ---- x2 = xl + aproj + bias; LN2 -> h2 (R2-proven) ----
__global__ __launch_bounds__(256) void k_ln2(const double* __restrict__ xl, const double* __restrict__ P2,
        const float* __restrict__ bap, const float* __restrict__ g2, const float* __restrict__ b2,
        double* __restrict__ x2, double* __restrict__ h2) {
    __shared__ double xs[DIM];
    __shared__ double sc[4];
    int b = blockIdx.x, tid = threadIdx.x;
    for (int i = tid; i < DIM; i += BD) {
        double s = xl[b * DIM + i] + (double)bap[i];
        for (int ks = 0; ks < 8; ++ks) s += P2[((size_t)(ks * 16 + b)) * DIM + i];
        xs[i] = s; x2[b * DIM + i] = s;
    }
    __syncthreads();
    double s = 0;
    for (int i = tid; i < DIM; i += BD) s += xs[i];
    s = block_sum(s, sc);
    double m = s * (1.0 / 1024.0);
    double ss = 0;
    for (int i = tid; i < DIM; i += BD) { double d = xs[i] - m; ss += d * d; }
    ss = block_sum(ss, sc);
    double r = 1.0 / sqrt(ss * (1.0 / 1024.0) + 1e-5);
    for (int i = tid; i < DIM; i += BD)
        h2[b * DIM + i] = (xs[i] - m) * r * (double)g2[i] + (double)b2[i];
}

// ---- m = gelu_new(fc + bias) (R2-proven) ----
__global__ __launch_bounds__(256) void k_gelu(const double* __restrict__ P3, const float* __restrict__ bfc,
                                              double* __restrict__ m) {
    int b = blockIdx.x;
    int i = blockIdx.y * BD + threadIdx.x;  // 0..4095
    double u = (double)bfc[i];
    for (int ks = 0; ks < 8; ++ks) u += P3[((size_t)(ks * 16 + b)) * 4096 + i];
    double c = sqrt(2.0 / M_PI);
    double inner = c * (u + 0.044715 * u * u * u);
    m[(size_t)b * 4096 + i] = 0.5 * u * (1.0 + tanh(inner));
}

// ---- x3 = x2 + mproj + bias; LNf -> hf (R2-proven) ----
__global__ __launch_bounds__(256) void k_lnf(const double* __restrict__ x2, const double* __restrict__ P4,
        const float* __restrict__ bmp, const float* __restrict__ gf, const float* __restrict__ bf,
        double* __restrict__ hf) {
    __shared__ double xs[DIM];
    __shared__ double sc[4];
    int b = blockIdx.x, tid = threadIdx.x;
    for (int i = tid; i < DIM; i += BD) {
        double s = x2[b * DIM + i] + (double)bmp[i];
        for (int ks = 0; ks < 32; ++ks) s += P4[((size_t)(ks * 16 + b)) * DIM + i];
        xs[i] = s;
    }
    __syncthreads();
    double s = 0;
    for (int i = tid; i < DIM; i += BD) s += xs[i];
    s = block_sum(s, sc);
    double m = s * (1.0 / 1024.0);
    double ss = 0;
    for (int i = tid; i < DIM; i += BD) { double d = xs[i] - m; ss += d * d; }
    ss = block_sum(ss, sc);
    double r = 1.0 / sqrt(ss * (1.0 / 1024.0) + 1e-5);
    for (int i = tid; i < DIM; i += BD)
        hf[b * DIM + i] = (xs[i] - m) * r * (double)gf[i] + (double)bf[i];
}

// ---- logits + threshold -> xl bits, X bitmask row, closed-form stats for new token ----
__global__ __launch_bounds__(256) void k_final(const double* __restrict__ P5, float* __restrict__ out,
        double* __restrict__ xl, unsigned long long* __restrict__ X,
        double* __restrict__ mu_pos, double* __restrict__ rs_pos, int t) {
    __shared__ unsigned long long Xs[8];
    int b = blockIdx.x, tid = threadIdx.x;
    int pos_new = 256 + t;
    if (tid < 8) Xs[tid] = 0ull;
    __syncthreads();
    for (int p = tid; p < NPROPS; p += BD) {
        double lg = 0;
        for (int ks = 0; ks < 8; ++ks) lg += P5[((size_t)(ks * 16 + b)) * NPROPS + p];
        out[((size_t)b * NSTEPS + t) * NPROPS + p] = (float)lg;
        xl[b * DIM + p] = 0.0;
        bool bit = (lg > 0.0);
        xl[b * DIM + 512 + p] = bit ? 1.0 : 0.0;
        if (bit) atomicOr(&Xs[p >> 6], 1ull << (p & 63));
    }
    __syncthreads();
    if (tid < XW)
        X[((size_t)b * SMAX + pos_new) * XW + tid] = (tid < 8) ? 0ull : Xs[tid - 8];
    if (tid == 0) {
        int nbi = 0;
        for (int w = 0; w < 8; ++w) nbi += __popcll(Xs[w]);
        double nb = (double)nbi;
        double m = nb * (1.0 / 1024.0);
        double var = ((1024.0 - nb) * m * m + nb * (1.0 - m) * (1.0 - m)) * (1.0 / 1024.0);
        mu_pos[b * SMAX + pos_new] = m;
        rs_pos[b * SMAX + pos_new] = 1.0 / sqrt(var + 1e-5);
    }
}

extern "C" void kernel_launch(void* const* d_in, const int* in_sizes, int n_in,
                              void* d_out, int out_size, void* d_ws, size_t ws_size,
                              hipStream_t stream) {
    const int*   tok  = (const int*)d_in[0];
    const float* Wqkv = (const float*)d_in[1];
    const float* bqkv = (const float*)d_in[2];
    const float* Wap  = (const float*)d_in[3];
    const float* bap  = (const float*)d_in[4];
    const float* g1   = (const float*)d_in[5];
    const float* b1   = (const float*)d_in[6];
    const float* g2   = (const float*)d_in[7];
    const float* b2   = (const float*)d_in[8];
    const float* Wfc  = (const float*)d_in[9];
    const float* bfc  = (const float*)d_in[10];
    const float* Wmp  = (const float*)d_in[11];
    const float* bmp  = (const float*)d_in[12];
    const float* gf   = (const float*)d_in[13];
    const float* bf   = (const float*)d_in[14];
    const float* Wsc  = (const float*)d_in[15];
    float* out = (float*)d_out;

    char* w = (char*)d_ws;
    size_t off = 0;
    auto alloc = [&](size_t bytes) -> void* {
        void* p = (void*)(w + off);
        off += (bytes + 255) & ~(size_t)255;
        return p;
    };
    unsigned long long* X = (unsigned long long*)alloc((size_t)NB * SMAX * XW * 8);
    double* mu_pos = (double*)alloc((size_t)NB * SMAX * 8);
    double* rs_pos = (double*)alloc((size_t)NB * SMAX * 8);
    double* xl   = (double*)alloc((size_t)NB * DIM * 8);
    double* c2   = (double*)alloc((size_t)NB * DIM * 8);
    double* alpha= (double*)alloc((size_t)NB * 8);
    double* x2   = (double*)alloc((size_t)NB * DIM * 8);
    double* h2   = (double*)alloc((size_t)NB * DIM * 8);
    double* mb   = (double*)alloc((size_t)NB * 4096 * 8);
    double* hf   = (double*)alloc((size_t)NB * DIM * 8);
    double* Pq   = (double*)alloc((size_t)8 * NB * DIM * 8);
    double* Pu   = (double*)alloc((size_t)8 * NB * DIM * 8);
    double* Pv   = (double*)alloc((size_t)8 * NB * DIM * 8);
    double* P2   = (double*)alloc((size_t)8 * NB * DIM * 8);
    double* P3   = (double*)alloc((size_t)8 * NB * 4096 * 8);
    double* P4   = (double*)alloc((size_t)32 * NB * DIM * 8);
    double* P5   = (double*)alloc((size_t)8 * NB * NPROPS * 8);
    double* G_K  = (double*)alloc(DIM * 8);
    double* KB   = (double*)alloc(DIM * 8);
    double* Gv   = (double*)alloc(DIM * 8);
    double* VB   = (double*)alloc(DIM * 8);
    signed char* tokc = (signed char*)alloc((size_t)NTOK);
    if (off > ws_size) return;  // fail visibly

    k_tok_convert<<<4096, BD, 0, stream>>>(tok, tokc);
    k_pack<<<1024, BD, 0, stream>>>(tokc, X);
    k_posstats<<<16, BD, 0, stream>>>(X, mu_pos, rs_pos);
    k_init<<<NB, BD, 0, stream>>>(tokc, xl);
    k_precomp<<<32, BD, 0, stream>>>(Wqkv, bqkv, g1, b1, G_K, KB, Gv, VB);

    for (int t = 0; t < NSTEPS; ++t) {
        int S = 256 + t, posq = 255 + t;
        k_q<<<dim3(16, 8), BD, 0, stream>>>(xl, mu_pos, rs_pos, posq, g1, b1, Wqkv, Pq);
        k_u<<<dim3(16, 8), BD, 0, stream>>>(Pq, bqkv, Wqkv, Pu);
        k_attn<<<NB, BD, 0, stream>>>(Pq, Pu, bqkv, g1, G_K, KB, X, mu_pos, rs_pos, c2, alpha, S);
        k_v<<<dim3(16, 8), BD, 0, stream>>>(c2, Wqkv, Gv, VB, alpha, Pv);
        k_aproj<<<dim3(16, 8), BD, 0, stream>>>(Pv, Wap, P2);
        k_ln2<<<NB, BD, 0, stream>>>(xl, P2, bap, g2, b2, x2, h2);
        mm16<<<dim3(64, 8), BD, 0, stream>>>(h2, 1024, Wfc, 4096, P3, 4096);
        k_gelu<<<dim3(NB, 16), BD, 0, stream>>>(P3, bfc, mb);
        mm16<<<dim3(16, 32), BD, 0, stream>>>(mb, 4096, Wmp, 1024, P4, 1024);
        k_lnf<<<NB, BD, 0, stream>>>(x2, P4, bmp, gf, bf, hf);
        mm16_t<<<dim3(8, 8), BD, 0, stream>>>(hf, 1024, Wsc, P5, 512);
        k_final<<<NB, BD, 0, stream>>>(P5, out, xl, X, mu_pos, rs_pos, t);
    }
}